// Round 6
// baseline (162.507 us; speedup 1.0000x reference)
//
#include <hip/hip_runtime.h>
#include <hip/hip_bf16.h>
#include <stdint.h>

static constexpr int M = 4096, N = 4096, K = 4096;
static constexpr float FP8_MAX = 448.0f;

using f32x16 = __attribute__((ext_vector_type(16))) float;
using i32x4  = __attribute__((ext_vector_type(4))) int;
using i32x8  = __attribute__((ext_vector_type(8))) int;

// ---------------- ws layout ----------------
static constexpr size_t AQ_OFF   = 0;
static constexpr size_t BQ_OFF   = (size_t)M * K;
static constexpr size_t AMAX_OFF = BQ_OFF + (size_t)N * K;

// ---------------- init ----------------
__global__ void init_amax_kernel(float* amax) {
    amax[0] = 0.0f;
    amax[1] = 0.0f;
}

// ---------------- amax reduction ----------------
__global__ __launch_bounds__(256) void amax_kernel(const float* __restrict__ x,
                                                   const float* __restrict__ w,
                                                   float* __restrict__ amax,
                                                   int n4_per_tensor,
                                                   int blocks_per_tensor) {
    const int tensor = blockIdx.x / blocks_per_tensor;
    const int blk    = blockIdx.x % blocks_per_tensor;
    const float4* src = (const float4*)(tensor == 0 ? x : w);

    float m = 0.0f;
    for (int i = blk * blockDim.x + threadIdx.x; i < n4_per_tensor;
         i += blocks_per_tensor * blockDim.x) {
        float4 v = src[i];
        m = fmaxf(m, fmaxf(fmaxf(fabsf(v.x), fabsf(v.y)),
                           fmaxf(fabsf(v.z), fabsf(v.w))));
    }
    #pragma unroll
    for (int off = 32; off >= 1; off >>= 1)
        m = fmaxf(m, __shfl_xor(m, off, 64));

    __shared__ float sm[4];
    const int lane = threadIdx.x & 63, wid = threadIdx.x >> 6;
    if (lane == 0) sm[wid] = m;
    __syncthreads();
    if (threadIdx.x == 0) {
        m = fmaxf(fmaxf(sm[0], sm[1]), fmaxf(sm[2], sm[3]));
        atomicMax((unsigned int*)&amax[tensor], __float_as_uint(m));
    }
}

// ---------------- quantize to fp8 e4m3fn ----------------
__global__ __launch_bounds__(256) void quant_kernel(const float* __restrict__ x,
                                                    const float* __restrict__ w,
                                                    unsigned char* __restrict__ aq,
                                                    unsigned char* __restrict__ bq,
                                                    const float* __restrict__ amax,
                                                    int n4_per_tensor) {
    int gid = blockIdx.x * blockDim.x + threadIdx.x;
    const int tensor = (gid >= n4_per_tensor) ? 1 : 0;
    const int i = tensor ? gid - n4_per_tensor : gid;

    const float inv = fmaxf(amax[tensor], 1e-12f) / FP8_MAX;
    const float4* src = (const float4*)(tensor == 0 ? x : w);
    int* dst = (int*)(tensor == 0 ? aq : bq);

    float4 v = src[i];
    float q0 = v.x / inv, q1 = v.y / inv, q2 = v.z / inv, q3 = v.w / inv;
    int packed = __builtin_amdgcn_cvt_pk_fp8_f32(q0, q1, 0, false);
    packed     = __builtin_amdgcn_cvt_pk_fp8_f32(q2, q3, packed, true);
    dst[i] = packed;
}

// ---------------- fp8 GEMM: A via LDS ring, B streamed to registers --------
// C[m][n] = sum_k Aq[m][k]*Bq[n][k];  out = C*scale + bias[n]
// 256x256 tile, 8 waves (2M x 4N), each 128x64; MX mfma 32x32x64, unit E8M0
// scales (math == non-scaled fp8).
//
// LDS holds ONLY A (DEPTH-4 ring x 16KB = 64KB); B fragments are loaded
// directly global->reg (row=lane&31 maps to [N][K] rows; 2x dwordx4 per
// frag), pipelined 2 tiles ahead in a static 4-slot register ring.
// Per-iter issues: {2 gld_lds A(t+3), 4 gload B(t+2)} = 6 vm-ops.
// Top-of-iter vmcnt(6) == {A(t+2), B(t+1)} outstanding -> A(t) in LDS and
// B(t) in regs. Loads never drain. lgkmcnt(0) before backedge (rule #18).
static constexpr int BM = 256, BN = 256, BK = 64, DEPTH = 4, NT = K / BK;

__device__ __forceinline__ void gld_lds16(const void* g, void* l) {
    __builtin_amdgcn_global_load_lds(
        (const __attribute__((address_space(1))) void*)g,
        (__attribute__((address_space(3))) void*)l, 16, 0, 0);
}

struct BReg { i32x4 lo0, hi0, lo1, hi1; };

__global__ __launch_bounds__(512, 2) void gemm_kernel(const unsigned char* __restrict__ Aq,
                                                      const unsigned char* __restrict__ Bq,
                                                      const float* __restrict__ amax,
                                                      const float* __restrict__ bias,
                                                      float* __restrict__ out) {
    __shared__ unsigned char lds[DEPTH][BM * BK];   // 64 KiB, A only

    const int tid  = threadIdx.x;
    const int lane = tid & 63;
    const int w    = tid >> 6;            // 0..7
    const int wr   = w >> 2, wc = w & 3;  // 2M x 4N waves, 128x64 each

    // XCD-aware swizzle (grid 256, bijective since 256 % 8 == 0)
    const int bid = blockIdx.x;
    const int swz = (bid & 7) * 32 + (bid >> 3);
    const int brow = (swz >> 4) * BM;
    const int bcol = (swz & 15) * BN;

    const float sx = fmaxf(amax[0], 1e-12f) / FP8_MAX;
    const float sw = fmaxf(amax[1], 1e-12f) / FP8_MAX;
    const float scale = sx * sw;

    // ---- A staging (pre-swizzled global chunk, linear LDS dest) ----
    const int r4    = lane >> 2;
    const int row0  = w * 16 + r4;
    const int chk   = ((lane & 3) ^ ((row0 >> 1) & 3)) * 16;
    const unsigned char* Abase = Aq + (size_t)brow * K;

    // ---- A fragment read offsets (32x32x64: row=lane&31, k=(lane>>5)*32) ----
    const int frow = lane & 31;
    const int swzr = (frow >> 1) & 3;
    const int c0   = (lane >> 5) * 2;
    const int off0 = ((c0 ^ swzr) << 4);
    const int off1 = (((c0 + 1) ^ swzr) << 4);

    // ---- B direct-load base pointers (per-lane rows of [N][K]) ----
    const unsigned char* Bp0 = Bq + (size_t)(bcol + wc * 64 + frow) * K      + (lane >> 5) * 32;
    const unsigned char* Bp1 = Bq + (size_t)(bcol + wc * 64 + 32 + frow) * K + (lane >> 5) * 32;

    f32x16 acc[4][2] = {};

#define STAGE_A(t, d)                                                                          \
    do {                                                                                       \
        const size_t _k0 = (size_t)(t) * BK;                                                   \
        gld_lds16(Abase + (size_t)row0 * K + _k0 + chk,         &lds[d][w * 1024]);            \
        gld_lds16(Abase + (size_t)(row0 + 128) * K + _k0 + chk, &lds[d][8192 + w * 1024]);     \
    } while (0)

#define GLOAD_B(t, BR)                                                         \
    do {                                                                       \
        const size_t _kb = (size_t)(t) * BK;                                   \
        BR.lo0 = *(const i32x4*)(Bp0 + _kb);                                   \
        BR.hi0 = *(const i32x4*)(Bp0 + _kb + 16);                              \
        BR.lo1 = *(const i32x4*)(Bp1 + _kb);                                   \
        BR.hi1 = *(const i32x4*)(Bp1 + _kb + 16);                              \
    } while (0)

#define ITER(t, rs, ss, BRcur, BRld)                                           \
    do {                                                                       \
        asm volatile("s_waitcnt vmcnt(6)" ::: "memory");                       \
        __builtin_amdgcn_s_barrier();                                          \
        STAGE_A(((t) + 3 < NT) ? (t) + 3 : NT - 1, ss);                        \
        GLOAD_B(((t) + 2 < NT) ? (t) + 2 : NT - 1, BRld);                      \
        i32x8 _aF[4];                                                          \
        _Pragma("unroll")                                                      \
        for (int _mt = 0; _mt < 4; ++_mt) {                                    \
            const unsigned char* _p = &lds[rs][(wr * 128 + _mt * 32 + frow) * BK]; \
            i32x4 _lo = *(const i32x4*)(_p + off0);                            \
            i32x4 _hi = *(const i32x4*)(_p + off1);                            \
            _aF[_mt] = __builtin_shufflevector(_lo, _hi, 0, 1, 2, 3, 4, 5, 6, 7); \
        }                                                                      \
        i32x8 _b0 = __builtin_shufflevector(BRcur.lo0, BRcur.hi0, 0, 1, 2, 3, 4, 5, 6, 7); \
        i32x8 _b1 = __builtin_shufflevector(BRcur.lo1, BRcur.hi1, 0, 1, 2, 3, 4, 5, 6, 7); \
        __builtin_amdgcn_s_setprio(1);                                         \
        _Pragma("unroll")                                                      \
        for (int _mt = 0; _mt < 4; ++_mt) {                                    \
            acc[_mt][0] = __builtin_amdgcn_mfma_scale_f32_32x32x64_f8f6f4(     \
                _aF[_mt], _b0, acc[_mt][0], 0, 0, 0, 0x7F, 0, 0x7F);           \
            acc[_mt][1] = __builtin_amdgcn_mfma_scale_f32_32x32x64_f8f6f4(     \
                _aF[_mt], _b1, acc[_mt][1], 0, 0, 0, 0x7F, 0, 0x7F);           \
        }                                                                      \
        __builtin_amdgcn_s_setprio(0);                                         \
        asm volatile("s_waitcnt lgkmcnt(0)" ::: "memory");                     \
        __builtin_amdgcn_sched_barrier(0);                                     \
    } while (0)

    BReg br0, br1, br2, br3;

    // prologue: A tiles 0,1,2 -> slots 0,1,2; B tiles 0,1 -> br0,br1
    STAGE_A(0, 0);
    GLOAD_B(0, br0);
    STAGE_A(1, 1);
    GLOAD_B(1, br1);
    STAGE_A(2, 2);

    for (int t = 0; t < NT; t += 4) {
        ITER(t + 0, 0, 3, br0, br2);
        ITER(t + 1, 1, 0, br1, br3);
        ITER(t + 2, 2, 1, br2, br0);
        ITER(t + 3, 3, 2, br3, br1);
    }
#undef ITER
#undef GLOAD_B
#undef STAGE_A

    // epilogue.  32x32 C/D: col=lane&31, row=(reg&3)+8*(reg>>2)+4*(lane>>5)
    #pragma unroll
    for (int mt = 0; mt < 4; ++mt) {
        const int rbase = brow + wr * 128 + mt * 32 + 4 * (lane >> 5);
        #pragma unroll
        for (int nt2 = 0; nt2 < 2; ++nt2) {
            const int col = bcol + wc * 64 + nt2 * 32 + (lane & 31);
            const float b = bias[col];
            #pragma unroll
            for (int reg = 0; reg < 16; ++reg) {
                const int row = rbase + (reg & 3) + 8 * (reg >> 2);
                out[(size_t)row * N + col] = acc[mt][nt2][reg] * scale + b;
            }
        }
    }
}

extern "C" void kernel_launch(void* const* d_in, const int* in_sizes, int n_in,
                              void* d_out, int out_size, void* d_ws, size_t ws_size,
                              hipStream_t stream) {
    const float* x    = (const float*)d_in[0];   // [4,1024,4096] f32 -> [4096][4096]
    const float* w    = (const float*)d_in[1];   // [4096][4096] f32
    const float* bias = (const float*)d_in[2];   // [4096] f32
    float* out = (float*)d_out;

    unsigned char* aq = (unsigned char*)d_ws + AQ_OFF;
    unsigned char* bq = (unsigned char*)d_ws + BQ_OFF;
    float* amax = (float*)((unsigned char*)d_ws + AMAX_OFF);

    const int n4 = (M * K) / 4;

    init_amax_kernel<<<1, 1, 0, stream>>>(amax);

    const int blocks_per_tensor = 512;
    amax_kernel<<<2 * blocks_per_tensor, 256, 0, stream>>>(x, w, amax, n4, blocks_per_tensor);

    const int quant_blocks = (2 * n4) / 256;
    quant_kernel<<<quant_blocks, 256, 0, stream>>>(x, w, aq, bq, amax, n4);

    gemm_kernel<<<256, 512, 0, stream>>>(aq, bq, amax, bias, out);
}

// Round 7
// 134.547 us; speedup vs baseline: 1.2078x; 1.2078x over previous
//
#include <hip/hip_runtime.h>
#include <hip/hip_bf16.h>
#include <stdint.h>

static constexpr int M = 4096, N = 4096, K = 4096;
static constexpr float FP8_MAX = 448.0f;

using f32x16 = __attribute__((ext_vector_type(16))) float;
using i32x4  = __attribute__((ext_vector_type(4))) int;
using i32x8  = __attribute__((ext_vector_type(8))) int;

// ---------------- ws layout ----------------
static constexpr size_t AQ_OFF   = 0;
static constexpr size_t BQ_OFF   = (size_t)M * K;
static constexpr size_t AMAX_OFF = BQ_OFF + (size_t)N * K;

// ---------------- init ----------------
__global__ void init_amax_kernel(float* amax) {
    amax[0] = 0.0f;
    amax[1] = 0.0f;
}

// ---------------- amax reduction ----------------
__global__ __launch_bounds__(256) void amax_kernel(const float* __restrict__ x,
                                                   const float* __restrict__ w,
                                                   float* __restrict__ amax,
                                                   int n4_per_tensor,
                                                   int blocks_per_tensor) {
    const int tensor = blockIdx.x / blocks_per_tensor;
    const int blk    = blockIdx.x % blocks_per_tensor;
    const float4* src = (const float4*)(tensor == 0 ? x : w);

    float m = 0.0f;
    for (int i = blk * blockDim.x + threadIdx.x; i < n4_per_tensor;
         i += blocks_per_tensor * blockDim.x) {
        float4 v = src[i];
        m = fmaxf(m, fmaxf(fmaxf(fabsf(v.x), fabsf(v.y)),
                           fmaxf(fabsf(v.z), fabsf(v.w))));
    }
    #pragma unroll
    for (int off = 32; off >= 1; off >>= 1)
        m = fmaxf(m, __shfl_xor(m, off, 64));

    __shared__ float sm[4];
    const int lane = threadIdx.x & 63, wid = threadIdx.x >> 6;
    if (lane == 0) sm[wid] = m;
    __syncthreads();
    if (threadIdx.x == 0) {
        m = fmaxf(fmaxf(sm[0], sm[1]), fmaxf(sm[2], sm[3]));
        atomicMax((unsigned int*)&amax[tensor], __float_as_uint(m));
    }
}

// ---------------- quantize to fp8 e4m3fn ----------------
__global__ __launch_bounds__(256) void quant_kernel(const float* __restrict__ x,
                                                    const float* __restrict__ w,
                                                    unsigned char* __restrict__ aq,
                                                    unsigned char* __restrict__ bq,
                                                    const float* __restrict__ amax,
                                                    int n4_per_tensor) {
    int gid = blockIdx.x * blockDim.x + threadIdx.x;
    const int tensor = (gid >= n4_per_tensor) ? 1 : 0;
    const int i = tensor ? gid - n4_per_tensor : gid;

    const float inv = fmaxf(amax[tensor], 1e-12f) / FP8_MAX;
    const float4* src = (const float4*)(tensor == 0 ? x : w);
    int* dst = (int*)(tensor == 0 ? aq : bq);

    float4 v = src[i];
    float q0 = v.x / inv, q1 = v.y / inv, q2 = v.z / inv, q3 = v.w / inv;
    int packed = __builtin_amdgcn_cvt_pk_fp8_f32(q0, q1, 0, false);
    packed     = __builtin_amdgcn_cvt_pk_fp8_f32(q2, q3, packed, true);
    dst[i] = packed;
}

// ---------------- fp8 GEMM: 256^2, DEPTH-4 ring, 2-phase double-barrier ----
// C[m][n] = sum_k Aq[m][k]*Bq[n][k];  out = C*scale + bias[n]
// 8 waves (2M x 4N), each 128x64 via 4x2 of 32x32; MX mfma 32x32x64, unit
// E8M0 scales (math == non-scaled fp8).
//
// Per K-tile t, TWO phases, each {issue ds_reads -> barrier -> lgkmcnt(0)
// -> setprio(1) MFMA x4 setprio(0) -> barrier}.  The double barrier gives a
// one-phase skew window: early waves issue next reads while late waves still
// MFMA (LDS pipe overlaps matrix pipe across waves — m201/m218 mechanism).
//   P1: read B(b0,b1) + A(mt0,mt1) of slot t&3; STAGE(t+3)->slot (t+3)&3;
//       [slot freed: all reads of tile t-1 drained before the tile t-1 final
//        barrier, which precedes this issue]
//       barrier; lgkmcnt(0); MFMA mt0/1 x b0/1; barrier
//   P2: read A(mt2,mt3); barrier; lgkmcnt(0); MFMA mt2/3 x b0/1;
//       vmcnt(8)   [stages t+1..t+3 = 12 loads issued; <=8 left => tile t+1
//                   landed FOR THIS WAVE]
//       barrier    [=> tile t+1 landed for ALL waves; P1(t+1) may read]
// Loads never drain to 0.  Unroll x4 so slot indices are compile-time.
static constexpr int BM = 256, BN = 256, BK = 64, DEPTH = 4, NT = K / BK;

__device__ __forceinline__ void gld_lds16(const void* g, void* l) {
    __builtin_amdgcn_global_load_lds(
        (const __attribute__((address_space(1))) void*)g,
        (__attribute__((address_space(3))) void*)l, 16, 0, 0);
}

__global__ __launch_bounds__(512, 2) void gemm_kernel(const unsigned char* __restrict__ Aq,
                                                      const unsigned char* __restrict__ Bq,
                                                      const float* __restrict__ amax,
                                                      const float* __restrict__ bias,
                                                      float* __restrict__ out) {
    __shared__ unsigned char lds[DEPTH][2][BM * BK];   // 128 KiB

    const int tid  = threadIdx.x;
    const int lane = tid & 63;
    const int w    = tid >> 6;            // 0..7
    const int wr   = w >> 2, wc = w & 3;  // 2M x 4N waves, 128x64 each

    // XCD-aware swizzle (grid 256, bijective since 256 % 8 == 0)
    const int bid = blockIdx.x;
    const int swz = (bid & 7) * 32 + (bid >> 3);
    const int brow = (swz >> 4) * BM;
    const int bcol = (swz & 15) * BN;

    const float sx = fmaxf(amax[0], 1e-12f) / FP8_MAX;
    const float sw = fmaxf(amax[1], 1e-12f) / FP8_MAX;
    const float scale = sx * sw;

    // ---- staging addresses (pre-swizzled global chunk, linear LDS dest) ----
    const int r4    = lane >> 2;
    const int row0  = w * 16 + r4;
    const int chk   = ((lane & 3) ^ ((row0 >> 1) & 3)) * 16;
    const unsigned char* Abase = Aq + (size_t)brow * K;
    const unsigned char* Bbase = Bq + (size_t)bcol * K;

    // ---- fragment read offsets (32x32x64: row=lane&31, k=(lane>>5)*32) ----
    const int frow = lane & 31;
    const int swzr = (frow >> 1) & 3;
    const int c0   = (lane >> 5) * 2;
    const int off0 = ((c0 ^ swzr) << 4);
    const int off1 = (((c0 + 1) ^ swzr) << 4);

    f32x16 acc[4][2] = {};

#define STAGE(t, d)                                                                            \
    do {                                                                                       \
        const size_t _k0 = (size_t)(t) * BK;                                                   \
        gld_lds16(Abase + (size_t)row0 * K + _k0 + chk,         &lds[d][0][w * 1024]);         \
        gld_lds16(Abase + (size_t)(row0 + 128) * K + _k0 + chk, &lds[d][0][8192 + w * 1024]);  \
        gld_lds16(Bbase + (size_t)row0 * K + _k0 + chk,         &lds[d][1][w * 1024]);         \
        gld_lds16(Bbase + (size_t)(row0 + 128) * K + _k0 + chk, &lds[d][1][8192 + w * 1024]);  \
    } while (0)

#define READ_FRAG(F, base_row, rs, ab)                                         \
    do {                                                                       \
        const unsigned char* _p = &lds[rs][ab][((base_row) + frow) * BK];      \
        i32x4 _lo = *(const i32x4*)(_p + off0);                                \
        i32x4 _hi = *(const i32x4*)(_p + off1);                                \
        F = __builtin_shufflevector(_lo, _hi, 0, 1, 2, 3, 4, 5, 6, 7);         \
    } while (0)

#define MXMFMA(a, b, c) \
    __builtin_amdgcn_mfma_scale_f32_32x32x64_f8f6f4((a), (b), (c), 0, 0, 0, 0x7F, 0, 0x7F)

#define ITER(t, rs, ss)                                                        \
    do {                                                                       \
        i32x8 _b0, _b1, _a0, _a1, _a2, _a3;                                    \
        /* ---- phase 1: issue ---- */                                         \
        READ_FRAG(_b0, wc * 64 +  0, rs, 1);                                   \
        READ_FRAG(_b1, wc * 64 + 32, rs, 1);                                   \
        READ_FRAG(_a0, wr * 128 +  0, rs, 0);                                  \
        READ_FRAG(_a1, wr * 128 + 32, rs, 0);                                  \
        STAGE(((t) + 3 < NT) ? (t) + 3 : NT - 1, ss);                          \
        __builtin_amdgcn_s_barrier();                                          \
        asm volatile("s_waitcnt lgkmcnt(0)" ::: "memory");                     \
        __builtin_amdgcn_s_setprio(1);                                         \
        acc[0][0] = MXMFMA(_a0, _b0, acc[0][0]);                               \
        acc[0][1] = MXMFMA(_a0, _b1, acc[0][1]);                               \
        acc[1][0] = MXMFMA(_a1, _b0, acc[1][0]);                               \
        acc[1][1] = MXMFMA(_a1, _b1, acc[1][1]);                               \
        __builtin_amdgcn_s_setprio(0);                                         \
        __builtin_amdgcn_s_barrier();                                          \
        /* ---- phase 2: issue ---- */                                         \
        READ_FRAG(_a2, wr * 128 + 64, rs, 0);                                  \
        READ_FRAG(_a3, wr * 128 + 96, rs, 0);                                  \
        __builtin_amdgcn_s_barrier();                                          \
        asm volatile("s_waitcnt lgkmcnt(0)" ::: "memory");                     \
        __builtin_amdgcn_s_setprio(1);                                         \
        acc[2][0] = MXMFMA(_a2, _b0, acc[2][0]);                               \
        acc[2][1] = MXMFMA(_a2, _b1, acc[2][1]);                               \
        acc[3][0] = MXMFMA(_a3, _b0, acc[3][0]);                               \
        acc[3][1] = MXMFMA(_a3, _b1, acc[3][1]);                               \
        __builtin_amdgcn_s_setprio(0);                                         \
        asm volatile("s_waitcnt vmcnt(8)" ::: "memory");                       \
        __builtin_amdgcn_s_barrier();                                          \
    } while (0)

    // prologue: tiles 0,1,2 -> slots 0,1,2; gate tile 0 for all waves
    STAGE(0, 0);
    STAGE(1, 1);
    STAGE(2, 2);
    asm volatile("s_waitcnt vmcnt(8)" ::: "memory");   // tile 0 landed (this wave)
    __builtin_amdgcn_s_barrier();                      // ... for all waves

    for (int t = 0; t < NT; t += 4) {
        ITER(t + 0, 0, 3);
        ITER(t + 1, 1, 0);
        ITER(t + 2, 2, 1);
        ITER(t + 3, 3, 2);
    }
#undef ITER
#undef MXMFMA
#undef READ_FRAG
#undef STAGE

    // epilogue.  32x32 C/D: col=lane&31, row=(reg&3)+8*(reg>>2)+4*(lane>>5)
    #pragma unroll
    for (int mt = 0; mt < 4; ++mt) {
        const int rbase = brow + wr * 128 + mt * 32 + 4 * (lane >> 5);
        #pragma unroll
        for (int nt2 = 0; nt2 < 2; ++nt2) {
            const int col = bcol + wc * 64 + nt2 * 32 + (lane & 31);
            const float b = bias[col];
            #pragma unroll
            for (int reg = 0; reg < 16; ++reg) {
                const int row = rbase + (reg & 3) + 8 * (reg >> 2);
                out[(size_t)row * N + col] = acc[mt][nt2][reg] * scale + b;
            }
        }
    }
}

extern "C" void kernel_launch(void* const* d_in, const int* in_sizes, int n_in,
                              void* d_out, int out_size, void* d_ws, size_t ws_size,
                              hipStream_t stream) {
    const float* x    = (const float*)d_in[0];   // [4,1024,4096] f32 -> [4096][4096]
    const float* w    = (const float*)d_in[1];   // [4096][4096] f32
    const float* bias = (const float*)d_in[2];   // [4096] f32
    float* out = (float*)d_out;

    unsigned char* aq = (unsigned char*)d_ws + AQ_OFF;
    unsigned char* bq = (unsigned char*)d_ws + BQ_OFF;
    float* amax = (float*)((unsigned char*)d_ws + AMAX_OFF);

    const int n4 = (M * K) / 4;

    init_amax_kernel<<<1, 1, 0, stream>>>(amax);

    const int blocks_per_tensor = 512;
    amax_kernel<<<2 * blocks_per_tensor, 256, 0, stream>>>(x, w, amax, n4, blocks_per_tensor);

    const int quant_blocks = (2 * n4) / 256;
    quant_kernel<<<quant_blocks, 256, 0, stream>>>(x, w, aq, bq, amax, n4);

    gemm_kernel<<<256, 512, 0, stream>>>(aq, bq, amax, bias, out);
}